// Round 9
// baseline (169.841 us; speedup 1.0000x reference)
//
#include <hip/hip_runtime.h>
#include <hip/hip_bf16.h>

#define B_  256
#define NH  256
#define NV  512
#define NT  768   // NV + NH
#define TPB 4     // 2 diag MFMA(+TR+mu) + 1 offdiag MFMA(+BL+mirror) + 1 corner

typedef __bf16 bf16x8 __attribute__((ext_vector_type(8)));
typedef float  f32x4  __attribute__((ext_vector_type(4)));

__device__ __forceinline__ __bf16 f2bf(float f) { return static_cast<__bf16>(f); }

__device__ __forceinline__ void nt_store4(float* p, f32x4 v) {
    __builtin_nontemporal_store(v, reinterpret_cast<f32x4*>(p));
}

// R7 (150.3us, nt-stores proven) + copy-band fold at zero extra reads:
//   tile 0,1 : diag 256^2 MFMA tile (B = scaled A, one panel read).
//              + top-right varvh^T for its 256 v-rows (from scaled Bs LDS,
//                256B-segment nt stores, per stage) + exact-f32 muv.
//   tile 2   : off-diag 256^2 MFMA tile (reads BOTH panels = all 512 cols).
//              + bottom-left varvh rows (exact f32 from registers, 1KB/wave
//                nt stores, per stage) + mirror via LDS transpose (nt).
//   tile 3   : bottom-right 256x256 corner (zeros + varh diag, nt) + muh.
// Copy bands eliminated: issued reads 1.5 -> 1.0 MB/batch (-131 MB device).
// XCD mapping: bid&7 == XCD; all 4 blocks of a batch share one XCD.
__global__ __launch_bounds__(512) void fused(const float* __restrict__ wt,
                                             const float* __restrict__ varh,
                                             const float* __restrict__ sig2,
                                             const float* __restrict__ bvec,
                                             const float* __restrict__ muh,
                                             float* __restrict__ out) {
    __shared__ __align__(16) char smem[76 * 1024];

    const int bid  = blockIdx.x;
    const int q    = bid >> 3;
    const int b    = (bid & 7) * 32 + (q >> 2);
    const int tile = q & 3;
    const int t    = threadIdx.x;

    const float* wtb  = wt + (size_t)b * NH * NV;
    float* mu   = out + (size_t)b * NT;
    float* varb = out + (size_t)B_ * NT + (size_t)b * NT * NT;

    if (tile < 3) {
        // ------------------- varv 256x256 MFMA tile -------------------
        const int  mt   = (tile == 1);
        const int  nt   = (tile != 0);
        const bool diag = (tile < 2);

        bf16x8 (*As)[256] = (bf16x8(*)[256])(smem);             // 32 KB
        bf16x8 (*Bs)[256] = (bf16x8(*)[256])(smem + 32 * 1024); // 32 KB
        float*  varh_s    = (float*)(smem + 64 * 1024);
        float*  muh_s     = (float*)(smem + 65 * 1024);
        float (*red)[256] = (float(*)[256])(smem + 66 * 1024);  // 8 KB

        const int m0 = mt * 256, n0 = nt * 256;
        const int lane = t & 63, wid = t >> 6;
        const int wm = wid >> 2, wn = wid & 3;   // wave tile 128x64
        const int mc = t & 63;   // staging m-chunk (4 floats)
        const int kb = t >> 6;   // staging k-chunk 0..7 (8 k-rows each)

        if (t < NH) { varh_s[t] = varh[b * NH + t]; muh_s[t] = muh[b * NH + t]; }

        f32x4 acc[8][4] = {};
        float acc_mu[4] = {0.f, 0.f, 0.f, 0.f};
        __syncthreads();

        for (int st = 0; st < 4; ++st) {
            const int k0 = st * 64;
            f32x4 av[8], bv[8];
            const float* baseA = wtb + (size_t)(k0 + kb * 8) * NV + m0 + 4 * mc;
#pragma unroll
            for (int j = 0; j < 8; ++j)
                av[j] = *reinterpret_cast<const f32x4*>(baseA + j * NV);
            if (!diag) {
                const float* baseB = wtb + (size_t)(k0 + kb * 8) * NV + n0 + 4 * mc;
#pragma unroll
                for (int j = 0; j < 8; ++j)
                    bv[j] = *reinterpret_cast<const f32x4*>(baseB + j * NV);
            }
            float sc[8];
#pragma unroll
            for (int j = 0; j < 8; ++j) sc[j] = varh_s[k0 + kb * 8 + j];

            if (diag) {   // exact-f32 muv partials (block-uniform branch)
#pragma unroll
                for (int j = 0; j < 8; ++j) {
                    const float mh = muh_s[k0 + kb * 8 + j];
#pragma unroll
                    for (int mj = 0; mj < 4; ++mj) acc_mu[mj] += av[j][mj] * mh;
                }
            } else {
                // bottom-left varvh rows (exact f32, 1KB/wave coalesced nt):
                // row NV+k, av covers cols 0..255, bv covers cols 256..511.
#pragma unroll
                for (int j = 0; j < 8; ++j) {
                    const int h = k0 + kb * 8 + j;
                    nt_store4(varb + (size_t)(NV + h) * NT + 4 * mc,
                              av[j] * sc[j]);
                    nt_store4(varb + (size_t)(NV + h) * NT + 256 + 4 * mc,
                              bv[j] * sc[j]);
                }
            }

            if (st) __syncthreads();   // prev stage's LDS reads done

#pragma unroll
            for (int mj = 0; mj < 4; ++mj) {
                bf16x8 pa, pb;
#pragma unroll
                for (int j = 0; j < 8; ++j) {
                    const float a  = av[j][mj];
                    const float bb = diag ? a : bv[j][mj];
                    pa[j] = f2bf(a);
                    pb[j] = f2bf(bb * sc[j]);
                }
                const int ca = 4 * mc + mj;
                const int ci = ca ^ ((ca >> 3) & 7);
                As[kb][ci] = pa;
                Bs[kb][ci] = pb;
            }
            __syncthreads();

#pragma unroll
            for (int kh = 0; kh < 2; ++kh) {
                const int ko = kh * 4 + (lane >> 4);
                bf16x8 af[8], bf4[4];
#pragma unroll
                for (int f = 0; f < 8; ++f) {
                    const int mi = wm * 128 + f * 16 + (lane & 15);
                    af[f] = As[ko][mi ^ ((mi >> 3) & 7)];
                }
#pragma unroll
                for (int f = 0; f < 4; ++f) {
                    const int ni = wn * 64 + f * 16 + (lane & 15);
                    bf4[f] = Bs[ko][ni ^ ((ni >> 3) & 7)];
                }
#pragma unroll
                for (int fm = 0; fm < 8; ++fm)
#pragma unroll
                    for (int fn = 0; fn < 4; ++fn)
                        acc[fm][fn] = __builtin_amdgcn_mfma_f32_16x16x32_bf16(
                            af[fm], bf4[fn], acc[fm][fn], 0, 0, 0);
            }

            if (diag) {
                // top-right varvh^T cols [NV+k0, NV+k0+64) from scaled Bs.
                // lane&7 = k-chunk: 8 lanes x 32B = 256B contiguous per v-row.
                const int kc = t & 7;          // k-chunk 0..7
                const int vo = t >> 3;         // 0..63
#pragma unroll
                for (int r = 0; r < 4; ++r) {
                    const int vv = r * 64 + vo;
                    const bf16x8 pv = Bs[kc][vv ^ ((vv >> 3) & 7)];
                    f32x4 lo, hi;
#pragma unroll
                    for (int e = 0; e < 4; ++e) {
                        lo[e] = (float)pv[e];
                        hi[e] = (float)pv[e + 4];
                    }
                    float* dst = varb + (size_t)(m0 + vv) * NT + NV + k0 + kc * 8;
                    nt_store4(dst, lo);
                    nt_store4(dst + 4, hi);
                }
            }
        }

        const float s2 = sig2[b];
#pragma unroll
        for (int fm = 0; fm < 8; ++fm) {
#pragma unroll
            for (int fn = 0; fn < 4; ++fn) {
                const int row = m0 + wm * 128 + fm * 16 + ((lane >> 4) << 2);
                const int col = n0 + wn * 64 + fn * 16 + (lane & 15);
                f32x4 v = acc[fm][fn];
                if (diag) {
                    const int dpos = col - row;
                    if (dpos >= 0 && dpos < 4) v[dpos] += s2;
                }
#pragma unroll
                for (int r = 0; r < 4; ++r)
                    varb[(size_t)(row + r) * NT + col] = v[r];
            }
        }

        if (diag) {   // finalize muv for columns m0..m0+255
#pragma unroll
            for (int mj = 0; mj < 4; ++mj) red[kb][4 * mc + mj] = acc_mu[mj];
            __syncthreads();
            if (t < 256) {
                float s = 0.f;
#pragma unroll
                for (int k = 0; k < 8; ++k) s += red[k][t];
                mu[m0 + t] = bvec[b * NV + m0 + t] + s;
            }
        } else {
            // mirror varv[n0+c][m0+m] via LDS transpose: 4 passes of 64 cols,
            // 1KB/wave coalesced nt stores.
            float (*trp)[260] = (float(*)[260])smem;   // 64 x 260 f32 = 65 KB
            for (int p = 0; p < 4; ++p) {
                __syncthreads();
                if (wn == p) {
#pragma unroll
                    for (int fm = 0; fm < 8; ++fm)
#pragma unroll
                        for (int fn = 0; fn < 4; ++fn) {
                            const int c = fn * 16 + (lane & 15);
                            const int m = wm * 128 + fm * 16 + ((lane >> 4) << 2);
                            *reinterpret_cast<f32x4*>(&trp[c][m]) = acc[fm][fn];
                        }
                }
                __syncthreads();
#pragma unroll
                for (int it = 0; it < 8; ++it) {
                    const int idx = it * 512 + t;
                    const int c   = idx >> 6;            // 0..63
                    const int m4  = (idx & 63) * 4;      // 0..252
                    f32x4 v = *reinterpret_cast<const f32x4*>(&trp[c][m4]);
                    nt_store4(varb + (size_t)(n0 + p * 64 + c) * NT + m0 + m4, v);
                }
            }
        }
    } else {
        // ------------- bottom-right 256x256 corner + muh copy -------------
        const int rr = t >> 6;            // 0..7
        const int c4 = (t & 63) * 4;      // 0..252
#pragma unroll
        for (int p = 0; p < 32; ++p) {
            const int row = rr + 8 * p;   // 0..255
            const int dpos = row - c4;
            f32x4 v = {0.f, 0.f, 0.f, 0.f};
            if (dpos >= 0 && dpos < 4) v[dpos] = varh[b * NH + row];
            nt_store4(varb + (size_t)(NV + row) * NT + NV + c4, v);
        }
        if (t < NH) mu[NV + t] = muh[b * NH + t];
    }
}

// ---------------------------------------------------------------------------
extern "C" void kernel_launch(void* const* d_in, const int* in_sizes, int n_in,
                              void* d_out, int out_size, void* d_ws, size_t ws_size,
                              hipStream_t stream) {
    (void)in_sizes; (void)n_in; (void)out_size; (void)d_ws; (void)ws_size;
    const float* wt   = (const float*)d_in[0];
    const float* varh = (const float*)d_in[1];
    const float* sig2 = (const float*)d_in[2];
    const float* bvec = (const float*)d_in[3];
    const float* muh  = (const float*)d_in[4];
    float* out = (float*)d_out;

    fused<<<B_ * TPB, 512, 0, stream>>>(wt, varh, sig2, bvec, muh, out);
}

// Round 10
// 131.803 us; speedup vs baseline: 1.2886x; 1.2886x over previous
//
#include <hip/hip_runtime.h>
#include <hip/hip_bf16.h>

#define B_  256
#define NH  256
#define NV  512
#define NT  768   // NV + NH
#define TPB 9     // 3 varv MFMA (2 diag + 1 offdiag) + 4 copy bands + 2 diag-region

typedef __bf16 bf16x8 __attribute__((ext_vector_type(8)));
typedef float  f32x4  __attribute__((ext_vector_type(4)));

__device__ __forceinline__ __bf16 f2bf(float f) { return static_cast<__bf16>(f); }

__device__ __forceinline__ void nt_store4(float* p, f32x4 v) {
    __builtin_nontemporal_store(v, reinterpret_cast<f32x4*>(p));
}

// R7 base (150.3us) + ONE change: MFMA-tile primary stores routed through an
// LDS transpose-stage so every tile row goes out as a 1KB-contiguous nt store
// (was: 64B segments through cached L2). Mechanism: (i) max DRAM segment size
// on the 256MB primary-tile stream, (ii) last L2-polluting stream removed ->
// XCD-pinned wt re-reads (copy bands + offdiag panels) can L2-hit.
// Per batch, 9 blocks @512thr:
//   tile 0,1 : diag 256^2 MFMA tile (B = scaled A); exact-f32 muv.
//   tile 2   : off-diag 256^2 MFMA tile; primary + mirror both via LDS (nt).
//   tile 3..6: copy band (64 h x 512 v): BL (nt) + TR via LDS transpose (nt).
//   tile 7,8 : diag-region rows (nt); tile 7 copies muh.
// XCD mapping: bid&7 == XCD; all 9 blocks of a batch share one XCD.
__global__ __launch_bounds__(512) void fused(const float* __restrict__ wt,
                                             const float* __restrict__ varh,
                                             const float* __restrict__ sig2,
                                             const float* __restrict__ bvec,
                                             const float* __restrict__ muh,
                                             float* __restrict__ out) {
    __shared__ __align__(16) char smem[78 * 1024];

    const int bid  = blockIdx.x;
    const int q    = bid >> 3;
    const int b    = (bid & 7) * 32 + q / TPB;
    const int tile = q % TPB;
    const int t    = threadIdx.x;

    const float* wtb  = wt + (size_t)b * NH * NV;
    float* mu   = out + (size_t)b * NT;
    float* varb = out + (size_t)B_ * NT + (size_t)b * NT * NT;

    if (tile < 3) {
        // ------------------- varv 256x256 MFMA tile -------------------
        const int  mt   = (tile == 1);
        const int  nt   = (tile != 0);
        const bool diag = (tile < 2);

        bf16x8 (*As)[256] = (bf16x8(*)[256])(smem);             // 32 KB
        bf16x8 (*Bs)[256] = (bf16x8(*)[256])(smem + 32 * 1024); // 32 KB
        float*  varh_s    = (float*)(smem + 67 * 1024);
        float*  muh_s     = (float*)(smem + 68 * 1024);
        float (*red)[256] = (float(*)[256])(smem + 69 * 1024);  // 8 KB

        const int m0 = mt * 256, n0 = nt * 256;
        const int lane = t & 63, wid = t >> 6;
        const int wm = wid >> 2, wn = wid & 3;   // wave tile 128x64
        const int mc = t & 63;   // staging m-chunk (4 floats)
        const int kb = t >> 6;   // staging k-chunk 0..7 (8 k-rows each)

        if (t < NH) { varh_s[t] = varh[b * NH + t]; muh_s[t] = muh[b * NH + t]; }

        f32x4 acc[8][4] = {};
        float acc_mu[4] = {0.f, 0.f, 0.f, 0.f};
        __syncthreads();

        for (int st = 0; st < 4; ++st) {
            const int k0 = st * 64;
            f32x4 av[8], bv[8];
            const float* baseA = wtb + (size_t)(k0 + kb * 8) * NV + m0 + 4 * mc;
#pragma unroll
            for (int j = 0; j < 8; ++j)
                av[j] = *reinterpret_cast<const f32x4*>(baseA + j * NV);
            if (!diag) {
                const float* baseB = wtb + (size_t)(k0 + kb * 8) * NV + n0 + 4 * mc;
#pragma unroll
                for (int j = 0; j < 8; ++j)
                    bv[j] = *reinterpret_cast<const f32x4*>(baseB + j * NV);
            }
            float sc[8];
#pragma unroll
            for (int j = 0; j < 8; ++j) sc[j] = varh_s[k0 + kb * 8 + j];

            if (diag) {   // exact-f32 muv partials (block-uniform branch)
#pragma unroll
                for (int j = 0; j < 8; ++j) {
                    const float mh = muh_s[k0 + kb * 8 + j];
#pragma unroll
                    for (int mj = 0; mj < 4; ++mj) acc_mu[mj] += av[j][mj] * mh;
                }
            }

            if (st) __syncthreads();   // prev stage's LDS reads done

#pragma unroll
            for (int mj = 0; mj < 4; ++mj) {
                bf16x8 pa, pb;
#pragma unroll
                for (int j = 0; j < 8; ++j) {
                    const float a  = av[j][mj];
                    const float bb = diag ? a : bv[j][mj];
                    pa[j] = f2bf(a);
                    pb[j] = f2bf(bb * sc[j]);
                }
                const int ca = 4 * mc + mj;
                const int ci = ca ^ ((ca >> 3) & 7);
                As[kb][ci] = pa;
                Bs[kb][ci] = pb;
            }
            __syncthreads();

#pragma unroll
            for (int kh = 0; kh < 2; ++kh) {
                const int ko = kh * 4 + (lane >> 4);
                bf16x8 af[8], bf4[4];
#pragma unroll
                for (int f = 0; f < 8; ++f) {
                    const int mi = wm * 128 + f * 16 + (lane & 15);
                    af[f] = As[ko][mi ^ ((mi >> 3) & 7)];
                }
#pragma unroll
                for (int f = 0; f < 4; ++f) {
                    const int ni = wn * 64 + f * 16 + (lane & 15);
                    bf4[f] = Bs[ko][ni ^ ((ni >> 3) & 7)];
                }
#pragma unroll
                for (int fm = 0; fm < 8; ++fm)
#pragma unroll
                    for (int fn = 0; fn < 4; ++fn)
                        acc[fm][fn] = __builtin_amdgcn_mfma_f32_16x16x32_bf16(
                            af[fm], bf4[fn], acc[fm][fn], 0, 0, 0);
            }
        }

        // sig2 on the diagonal (diag tiles only), in-register
        if (diag) {
            const float s2 = sig2[b];
#pragma unroll
            for (int fm = 0; fm < 8; ++fm)
#pragma unroll
                for (int fn = 0; fn < 4; ++fn) {
                    const int row = m0 + wm * 128 + fm * 16 + ((lane >> 4) << 2);
                    const int col = n0 + wn * 64 + fn * 16 + (lane & 15);
                    const int dpos = col - row;
                    if (dpos >= 0 && dpos < 4) acc[fm][fn][dpos] += s2;
                }
        }

        // ---- primary tile stores via LDS: 4 passes of 64 rows, each row
        // ---- goes out as one 1KB-contiguous nt segment (was 64B segments).
        {
            float (*trp)[260] = (float(*)[260])smem;   // 64 x 260 f32 = 65 KB
            for (int p = 0; p < 4; ++p) {
                __syncthreads();
                if (wm == (p >> 1)) {
                    const int fbase = (p & 1) * 4;
#pragma unroll
                    for (int ff = 0; ff < 4; ++ff)
#pragma unroll
                        for (int fn = 0; fn < 4; ++fn) {
                            const int rl = ff * 16 + ((lane >> 4) << 2);
                            const int c  = wn * 64 + fn * 16 + (lane & 15);
                            const f32x4 v = acc[fbase + ff][fn];
#pragma unroll
                            for (int r = 0; r < 4; ++r) trp[rl + r][c] = v[r];
                        }
                }
                __syncthreads();
#pragma unroll
                for (int it = 0; it < 8; ++it) {
                    const int row = it * 8 + wid;        // 0..63
                    const int m4  = (t & 63) * 4;        // 0..252
                    f32x4 v = *reinterpret_cast<const f32x4*>(&trp[row][m4]);
                    nt_store4(varb + (size_t)(m0 + p * 64 + row) * NT + n0 + m4, v);
                }
            }
        }

        if (diag) {   // finalize muv for columns m0..m0+255
            __syncthreads();
#pragma unroll
            for (int mj = 0; mj < 4; ++mj) red[kb][4 * mc + mj] = acc_mu[mj];
            __syncthreads();
            if (t < 256) {
                float s = 0.f;
#pragma unroll
                for (int k = 0; k < 8; ++k) s += red[k][t];
                mu[m0 + t] = bvec[b * NV + m0 + t] + s;
            }
        } else {
            // mirror varv[n0+c][m0+m] via LDS transpose: 4 passes of 64 cols,
            // 1KB/wave coalesced nt stores.
            float (*trp)[260] = (float(*)[260])smem;   // 64 x 260 f32 = 65 KB
            for (int p = 0; p < 4; ++p) {
                __syncthreads();
                if (wn == p) {
#pragma unroll
                    for (int fm = 0; fm < 8; ++fm)
#pragma unroll
                        for (int fn = 0; fn < 4; ++fn) {
                            const int c = fn * 16 + (lane & 15);
                            const int m = wm * 128 + fm * 16 + ((lane >> 4) << 2);
                            *reinterpret_cast<f32x4*>(&trp[c][m]) = acc[fm][fn];
                        }
                }
                __syncthreads();
#pragma unroll
                for (int it = 0; it < 8; ++it) {
                    const int idx = it * 512 + t;
                    const int c   = idx >> 6;            // 0..63
                    const int m4  = (idx & 63) * 4;      // 0..252
                    f32x4 v = *reinterpret_cast<const f32x4*>(&trp[c][m4]);
                    nt_store4(varb + (size_t)(n0 + p * 64 + c) * NT + m0 + m4, v);
                }
            }
        }
    } else if (tile < 7) {
        // ------------- copy band: 64 h-rows x 512 v (BL + TR) -------------
        const int h0 = (tile - 3) * 64;
        float (*tl)[64][65] = (float(*)[64][65])smem;   // 2 x 64x65 f32, 33 KB
        const int sub = t >> 8;          // 0..1 (two subtiles in parallel)
        const int tt  = t & 255;
        const int r   = tt >> 4;         // 0..15
        const int c4  = (tt & 15) * 4;   // 0..60

        for (int iter = 0; iter < 4; ++iter) {
            const int v0 = iter * 128 + sub * 64;
            if (iter) __syncthreads();   // prev iter's reads done
#pragma unroll
            for (int p = 0; p < 4; ++p) {
                const int h = h0 + r + 16 * p;
                const float vh = varh[b * NH + h];
                f32x4 x = *reinterpret_cast<const f32x4*>(
                    wtb + (size_t)h * NV + v0 + c4);
                x *= vh;
                nt_store4(varb + (size_t)(NV + h) * NT + v0 + c4, x);  // bottom-left
                tl[sub][r + 16 * p][c4 + 0] = x[0];
                tl[sub][r + 16 * p][c4 + 1] = x[1];
                tl[sub][r + 16 * p][c4 + 2] = x[2];
                tl[sub][r + 16 * p][c4 + 3] = x[3];
            }
            __syncthreads();
#pragma unroll
            for (int p = 0; p < 4; ++p) {
                const int vrow = v0 + r + 16 * p;
                f32x4 y;
                y[0] = tl[sub][c4 + 0][r + 16 * p];
                y[1] = tl[sub][c4 + 1][r + 16 * p];
                y[2] = tl[sub][c4 + 2][r + 16 * p];
                y[3] = tl[sub][c4 + 3][r + 16 * p];
                nt_store4(varb + (size_t)vrow * NT + NV + h0 + c4, y);  // top-right
            }
        }
    } else {
        // ------------------- diag-region rows (128 x 256) -------------------
        const int d  = tile - 7;          // 0..1
        const int r0 = NV + d * 128;
        const int rr = t >> 6;            // 0..7
        const int c4 = (t & 63) * 4;      // 0..252
#pragma unroll
        for (int p = 0; p < 16; ++p) {
            const int row = rr + 8 * p;   // 0..127
            const int g   = d * 128 + row;
            const int dpos = g - c4;
            const float val = (dpos >= 0 && dpos < 4) ? varh[b * NH + g] : 0.f;
            f32x4 v;
            v[0] = (dpos == 0) ? val : 0.f;
            v[1] = (dpos == 1) ? val : 0.f;
            v[2] = (dpos == 2) ? val : 0.f;
            v[3] = (dpos == 3) ? val : 0.f;
            nt_store4(varb + (size_t)(r0 + row) * NT + NV + c4, v);
        }
        if (d == 0 && t < NH) mu[NV + t] = muh[b * NH + t];
    }
}

// ---------------------------------------------------------------------------
extern "C" void kernel_launch(void* const* d_in, const int* in_sizes, int n_in,
                              void* d_out, int out_size, void* d_ws, size_t ws_size,
                              hipStream_t stream) {
    (void)in_sizes; (void)n_in; (void)out_size; (void)d_ws; (void)ws_size;
    const float* wt   = (const float*)d_in[0];
    const float* varh = (const float*)d_in[1];
    const float* sig2 = (const float*)d_in[2];
    const float* bvec = (const float*)d_in[3];
    const float* muh  = (const float*)d_in[4];
    float* out = (float*)d_out;

    fused<<<B_ * TPB, 512, 0, stream>>>(wt, varh, sig2, bvec, muh, out);
}